// Round 5
// baseline (342.464 us; speedup 1.0000x reference)
//
#include <hip/hip_runtime.h>

// SimpleHashEncoder1D: out[n, l*2+f] = hash_table[floor(xn*scale[l]+0.5) & (T-1)][f]
// xn = (x+bound)/(2*bound), scale[l] = 16*b^l - 1, b = expf((logf(2^19)-logf(16))/15)
//
// float32 bit-exactness (verified R1, absmax == 0.0):
//   b = 0x3FFFFFFF = 2 - 2^-23   (NOT 2.0: correctly-rounded f32 log/exp chain)
//   fl32(b^l) = 2^l * (1 - l*2^-24)            (exact)
//   scale[l]  = (2^(l+4) - 1) - l*2^(l-20)     (exactly representable)
//   bits(scale[l]) = ((130+l)<<23) | (0x800000 - (0x100000>>l) - l)
// Separate mul/add (numpy does not fuse); __fdiv_rn for the normalize.
// Indices provably in [0, 2^19) -> '& (T-1)' == '% T'.
//
// Ledger: R4 (4x MLP) 338 best. R5 (plain stores) 344 ~noise. R6 (sc0 all
// levels) 371 (+16.8M L2 probes -> +32us). R7 (selective sc0) 341 ~noise.
// Only intervention that moved time was the one that changed L2 REQUEST
// COUNT -> kernel is TCC request-rate bound (~38M requests at ~270 G req/s
// ~= 140us, matching observed ~160).
//
// R8 (this round): LDS-SERVE LEVELS 0..10. idx_l = floor(xn*scale_l+0.5)
// <= 2^(l+4)-1, so the working sets NEST: levels 0..10 all index
// table[0..16384) = 128 KiB, which fits LDS. Stage once per block (float4
// streaming, ~2M total requests), serve 11/16 levels from LDS. L2 random
// gathers drop 33.5M -> 10.5M; total TCC load halves. LDS side ~4us
// (21M ds_read_b64 over 256 CUs, random-bank). Occupancy 1 blk/CU
// (16 waves) — fine, fills hit BW peak at 10% occupancy and R4 proved
// latency isn't the limit. Level split: j<=4 both LDS; j==5 level 10 LDS,
// level 11 global; j>=6 both global. nt x-loads + nt stores (R4 config).

constexpr int T_SIZE = 524288;   // 2^19
constexpr int N_PTS  = 2097152;  // 2^21
constexpr int SLOTS  = N_PTS * 8;      // 2^24 float4 output slots
constexpr int KI     = 8;              // slots per thread
constexpr int NTH    = SLOTS / KI;     // 2^21 threads
constexpr int BLK    = 1024;
constexpr int LUT_N  = 16384;          // staged entries = 128 KiB (levels<=10)

typedef float vfloat4 __attribute__((ext_vector_type(4)));

__device__ __forceinline__ float scale_for_level(int l) {
    unsigned bits = ((130u + (unsigned)l) << 23)
                  | (0x800000u - (0x100000u >> l) - (unsigned)l);
    return __uint_as_float(bits);
}

__global__ __launch_bounds__(BLK) void hash_encode_kernel(
    const float* __restrict__ x,
    const float* __restrict__ table,
    const int* __restrict__ bound_p,
    float* __restrict__ out)
{
    __shared__ float2 lut[LUT_N];   // 128 KiB: table[0..16384), bit-identical

    // ---- stage: 8192 float4 = 128 KiB, coalesced, 8 iters x 1024 thr ----
    {
        const vfloat4* src = (const vfloat4*)table;
        vfloat4*       dst = (vfloat4*)lut;
#pragma unroll
        for (int m = 0; m < LUT_N / 2 / BLK; ++m) {
            int i4 = threadIdx.x + m * BLK;
            dst[i4] = src[i4];
        }
    }

    int tid = blockIdx.x * BLK + threadIdx.x;   // 2^21 threads
    // NTH is a multiple of 8 -> slot (tid + k*NTH) has the same low 3 bits
    // for all k: one level-pair (2j, 2j+1) per thread.
    int j  = tid & 7;
    float s0 = scale_for_level(j << 1);
    float s1 = scale_for_level((j << 1) + 1);
    float fb  = (float)bound_p[0];
    float fb2 = __fmul_rn(2.0f, fb);

    __syncthreads();

    const float2* t2 = (const float2*)table;
    vfloat4* o4 = (vfloat4*)out;

    // 8 slots per thread, two register-sized groups of 4
#pragma unroll
    for (int g = 0; g < 2; ++g) {
        // Phase 1: x loads (streamed once, don't cache)
        float xv[4];
#pragma unroll
        for (int k = 0; k < 4; ++k) {
            int slot = tid + (g * 4 + k) * NTH;
            xv[k] = __builtin_nontemporal_load(&x[slot >> 3]);
        }

        // Phase 2: indices. xs >= 0.5 always -> int-trunc == floor; < 2^19
        // so '&' is exact mod.
        int i0[4], i1[4];
#pragma unroll
        for (int k = 0; k < 4; ++k) {
            float xn  = __fdiv_rn(__fadd_rn(xv[k], fb), fb2);
            float xs0 = __fadd_rn(__fmul_rn(xn, s0), 0.5f);
            float xs1 = __fadd_rn(__fmul_rn(xn, s1), 0.5f);
            i0[k] = ((int)xs0) & (T_SIZE - 1);
            i1[k] = ((int)xs1) & (T_SIZE - 1);
        }

        // Phase 3: gathers. Levels <=10 provably have idx < 16384 -> LDS.
        float2 a[4], b[4];
        if (j <= 4) {                       // levels 0..9: both LDS
#pragma unroll
            for (int k = 0; k < 4; ++k) { a[k] = lut[i0[k]]; b[k] = lut[i1[k]]; }
        } else if (j == 5) {                // level 10 LDS, level 11 global
#pragma unroll
            for (int k = 0; k < 4; ++k) { a[k] = lut[i0[k]]; b[k] = t2[i1[k]]; }
        } else {                            // levels 12..15: both global
#pragma unroll
            for (int k = 0; k < 4; ++k) { a[k] = t2[i0[k]]; b[k] = t2[i1[k]]; }
        }

        // Phase 4: coalesced nt stores (stream past L2; L2 belongs to the
        // remaining fine-level gathers)
#pragma unroll
        for (int k = 0; k < 4; ++k) {
            vfloat4 o;
            o.x = a[k].x; o.y = a[k].y; o.z = b[k].x; o.w = b[k].y;
            __builtin_nontemporal_store(o, o4 + (tid + (g * 4 + k) * NTH));
        }
    }
}

extern "C" void kernel_launch(void* const* d_in, const int* in_sizes, int n_in,
                              void* d_out, int out_size, void* d_ws, size_t ws_size,
                              hipStream_t stream) {
    const float* x     = (const float*)d_in[0];
    const float* table = (const float*)d_in[1];
    const int*   bound = (const int*)d_in[2];
    float* out = (float*)d_out;

    int blocks = NTH / BLK;                    // 2048
    hash_encode_kernel<<<blocks, BLK, 0, stream>>>(x, table, bound, out);
}